// Round 1
// 125.607 us; speedup vs baseline: 1.0340x; 1.0340x over previous
//
#include <hip/hip_runtime.h>

// toy_gnn scatter-add: out[dst[e], f] += w_mp * edge_weight[e] * x[src[e], f]
// N=100000, E=1600000, F=32, fp32.
//
// Round 8: remove redundant passes.
//   R7 analysis: both main kernels < 43us (absent from top-5 vs 43us harness
//   poison fills); HBM floor is ~11us -> latency/redundant-work bound.
//   Changes vs R7:
//   (1) sort_gather SUBS=4 -> 1: one 1024-thread block per coarse bucket.
//       Records read ONCE from global into registers (was: 4 sub-blocks each
//       scanning the whole bucket + ballot-compact + double LDS staging
//       mine->sorted). Deletes 75% of record re-reads (~38 MB) and half the
//       LDS traffic. Occupancy unchanged: 2 blocks x 16 waves = 32 waves/CU.
//   (2) bin_edges reshaped to exactly 256 blocks (chunk 6250, EPT 13):
//       100% CU coverage (was 196 blocks = 77%); run density 21 -> 16 recs
//       (128B, one cacheline) stays far above the R5 regression regime.
//   (3) init_cursors kernel -> hipMemsetAsync (cursors are counts now).
//   Kept: R4 coarse 256-node record layout, register accumulation (R5),
//   no LDS fp32 atomics (R6 lesson).

constexpr int N_NODES = 100000;
constexpr int N_EDGES = 1600000;
constexpr int F_DIM   = 32;

// ---- binning (coarse) ----
constexpr int NPB_C = 256;                           // nodes per coarse bucket
constexpr int NB_C  = (N_NODES + NPB_C - 1) / NPB_C; // 391
constexpr int CAP_C = 4608;                          // mean 4096 + 8 sigma(64)

constexpr int BIN_THREADS = 512;
constexpr int BIN_BLOCKS  = 256;                     // exactly one per CU
constexpr int BIN_CHUNK   = N_EDGES / BIN_BLOCKS;    // 6250 (exact: 256*6250=1.6M)
constexpr int BIN_EPT     = (BIN_CHUNK + BIN_THREADS - 1) / BIN_THREADS;  // 13

// ---- fused sort+gather ----
constexpr int AGG_THREADS = 1024;                    // 16 waves
constexpr int GRPT = (CAP_C + AGG_THREADS - 1) / AGG_THREADS;  // 5

// ---------------- workspace layout (bytes) ----------------
constexpr size_t WS_CURSOR  = 0;                     // NB_C ints (counts)
constexpr size_t WS_RECORDS = 4096;                  // NB_C*CAP_C uint2
constexpr size_t WS_NEEDED  = WS_RECORDS + (size_t)NB_C * CAP_C * 8;  // ~14.4 MB

__global__ __launch_bounds__(BIN_THREADS) void bin_edges(
    const int* __restrict__ src, const int* __restrict__ dst,
    const float* __restrict__ ew, const float* __restrict__ w_mp,
    int* __restrict__ gcursor, uint2* __restrict__ records)
{
    __shared__ int lhist[NB_C];
    __shared__ int lbase[NB_C];
    if (threadIdx.x < NB_C) lhist[threadIdx.x] = 0;
    __syncthreads();

    const float w = w_mp[0];
    const int base_e = blockIdx.x * BIN_CHUNK;
    const int e_end  = min(base_e + BIN_CHUNK, N_EDGES);
    int   bkt[BIN_EPT];
    uint2 rec[BIN_EPT];

    #pragma unroll
    for (int i = 0; i < BIN_EPT; ++i) {
        int e = base_e + threadIdx.x + i * BIN_THREADS;
        bkt[i] = -1;
        if (e < e_end) {
            int d = dst[e];
            int b = d >> 8;                     // coarse bucket (256 nodes)
            bkt[i] = b;
            rec[i].x = __float_as_uint(w * ew[e]);
            rec[i].y = (unsigned)src[e] | ((unsigned)(d & 255) << 24);
            atomicAdd(&lhist[b], 1);
        }
    }
    __syncthreads();

    if (threadIdx.x < NB_C) {
        int c = lhist[threadIdx.x];
        int base = c ? atomicAdd(&gcursor[threadIdx.x], c) : 0;
        lbase[threadIdx.x] = threadIdx.x * CAP_C + base;
        lhist[threadIdx.x] = 0;
    }
    __syncthreads();

    #pragma unroll
    for (int i = 0; i < BIN_EPT; ++i) {
        int b = bkt[i];
        if (b >= 0) {
            int pos = lbase[b] + atomicAdd(&lhist[b], 1);
            if (pos < (b + 1) * CAP_C)          // overflow guard (8-sigma margin)
                records[pos] = rec[i];
        }
    }
}

__global__ __launch_bounds__(AGG_THREADS) void sort_gather(
    const int*   __restrict__ gcursor,
    const uint2* __restrict__ records,
    const float* __restrict__ x,
    float*       __restrict__ out)
{
    __shared__ uint2 sorted[CAP_C];      // 36.9 KB node-sorted records
    __shared__ int   hist[NPB_C];
    __shared__ int   offs[NPB_C + 1];
    __shared__ int   cursor[NPB_C];

    const int coarse = blockIdx.x;
    const int t      = threadIdx.x;

    if (t < NPB_C) hist[t] = 0;
    __syncthreads();

    // --- single global pass: records -> registers, histogram nodes ---
    const int rbase = coarse * CAP_C;
    const int cnt   = min(gcursor[coarse], CAP_C);

    uint2 rec[GRPT];
    #pragma unroll
    for (int i = 0; i < GRPT; ++i) {
        int j = t + i * AGG_THREADS;
        rec[i].y = 0xFFFFFFFFu;             // "empty" (src < 2^24 -> unambiguous)
        if (j < cnt) {
            rec[i] = records[rbase + j];
            atomicAdd(&hist[rec[i].y >> 24], 1);
        }
    }
    __syncthreads();

    // --- exclusive scan of 256 counters (wave 0, 4 per lane) ---
    if (t < 64) {
        const int b4 = t * 4;
        int h0 = hist[b4], h1 = hist[b4 + 1], h2 = hist[b4 + 2], h3 = hist[b4 + 3];
        int s   = h0 + h1 + h2 + h3;
        int inc = s;
        #pragma unroll
        for (int d = 1; d < 64; d <<= 1) {
            int o = __shfl_up(inc, d, 64);
            if (t >= d) inc += o;
        }
        int base = inc - s;                 // exclusive prefix of 4-groups
        offs[b4]     = base;
        offs[b4 + 1] = base + h0;
        offs[b4 + 2] = base + h0 + h1;
        offs[b4 + 3] = base + h0 + h1 + h2;
        cursor[b4]     = base;
        cursor[b4 + 1] = base + h0;
        cursor[b4 + 2] = base + h0 + h1;
        cursor[b4 + 3] = base + h0 + h1 + h2;
        if (t == 63) offs[NPB_C] = inc;
    }
    __syncthreads();

    // --- scatter registers -> sorted LDS (counting sort by node, 8 bits) ---
    #pragma unroll
    for (int i = 0; i < GRPT; ++i) {
        if (rec[i].y != 0xFFFFFFFFu) {
            int slot = atomicAdd(&cursor[rec[i].y >> 24], 1);
            sorted[slot] = rec[i];
        }
    }
    __syncthreads();

    // --- gather: 8 threads/node, register acc, 4-way unrolled x-loads ---
    const int qq = (t & 7) * 4;
    #pragma unroll
    for (int p = 0; p < 2; ++p) {
        const int node  = p * (AGG_THREADS / 8) + (t >> 3);
        const int gnode = coarse * NPB_C + node;
        if (gnode >= N_NODES) continue;

        int j  = offs[node];
        int je = offs[node + 1];
        float4 acc = make_float4(0.f, 0.f, 0.f, 0.f);

        for (; j + 4 <= je; j += 4) {
            uint2 r0 = sorted[j + 0];
            uint2 r1 = sorted[j + 1];
            uint2 r2 = sorted[j + 2];
            uint2 r3 = sorted[j + 3];
            const float4 v0 = *reinterpret_cast<const float4*>(
                x + (size_t)(r0.y & 0xFFFFFFu) * F_DIM + qq);
            const float4 v1 = *reinterpret_cast<const float4*>(
                x + (size_t)(r1.y & 0xFFFFFFu) * F_DIM + qq);
            const float4 v2 = *reinterpret_cast<const float4*>(
                x + (size_t)(r2.y & 0xFFFFFFu) * F_DIM + qq);
            const float4 v3 = *reinterpret_cast<const float4*>(
                x + (size_t)(r3.y & 0xFFFFFFu) * F_DIM + qq);
            float c0 = __uint_as_float(r0.x), c1 = __uint_as_float(r1.x);
            float c2 = __uint_as_float(r2.x), c3 = __uint_as_float(r3.x);
            acc.x += c0 * v0.x + c1 * v1.x + c2 * v2.x + c3 * v3.x;
            acc.y += c0 * v0.y + c1 * v1.y + c2 * v2.y + c3 * v3.y;
            acc.z += c0 * v0.z + c1 * v1.z + c2 * v2.z + c3 * v3.z;
            acc.w += c0 * v0.w + c1 * v1.w + c2 * v2.w + c3 * v3.w;
        }
        for (; j < je; ++j) {
            uint2 r = sorted[j];
            float c = __uint_as_float(r.x);
            const float4 v = *reinterpret_cast<const float4*>(
                x + (size_t)(r.y & 0xFFFFFFu) * F_DIM + qq);
            acc.x += c * v.x;
            acc.y += c * v.y;
            acc.z += c * v.z;
            acc.w += c * v.w;
        }
        *reinterpret_cast<float4*>(out + (size_t)gnode * F_DIM + qq) = acc;
    }
}

// ---------------- fallback (R0): plain atomic scatter ----------------
__global__ __launch_bounds__(256) void gnn_scatter_atomic(
    const float* __restrict__ x, const int* __restrict__ src,
    const int* __restrict__ dst, const float* __restrict__ ew,
    const float* __restrict__ w_mp, float* __restrict__ out)
{
    const float w = w_mp[0];
    int gid = blockIdx.x * blockDim.x + threadIdx.x;
    int e = gid >> 3;
    int qq = (gid & 7) * 4;
    if (e >= N_EDGES) return;
    int s = src[e];
    int d = dst[e];
    float c = w * ew[e];
    const float4 xv = *reinterpret_cast<const float4*>(x + (size_t)s * F_DIM + qq);
    float* op = out + (size_t)d * F_DIM + qq;
    atomicAdd(op + 0, c * xv.x);
    atomicAdd(op + 1, c * xv.y);
    atomicAdd(op + 2, c * xv.z);
    atomicAdd(op + 3, c * xv.w);
}

extern "C" void kernel_launch(void* const* d_in, const int* in_sizes, int n_in,
                              void* d_out, int out_size, void* d_ws, size_t ws_size,
                              hipStream_t stream) {
    const float* x    = (const float*)d_in[0];
    const int*   ei   = (const int*)d_in[1];   // [2, E]: src row, then dst row
    const float* ew   = (const float*)d_in[2];
    const float* w_mp = (const float*)d_in[3];
    float* out = (float*)d_out;

    const int* src = ei;
    const int* dst = ei + N_EDGES;

    if (ws_size < WS_NEEDED) {
        hipMemsetAsync(d_out, 0, (size_t)out_size * sizeof(float), stream);
        int total = N_EDGES * 8;
        gnn_scatter_atomic<<<(total + 255) / 256, 256, 0, stream>>>(
            x, src, dst, ew, w_mp, out);
        return;
    }

    char* ws = (char*)d_ws;
    int*   gcursor = (int*)(ws + WS_CURSOR);
    uint2* records = (uint2*)(ws + WS_RECORDS);

    hipMemsetAsync(gcursor, 0, NB_C * sizeof(int), stream);
    bin_edges<<<BIN_BLOCKS, BIN_THREADS, 0, stream>>>(src, dst, ew, w_mp,
                                                      gcursor, records);
    sort_gather<<<NB_C, AGG_THREADS, 0, stream>>>(gcursor, records, x, out);
    // sort_gather writes every out element -> no d_out memset needed
}

// Round 2
// 121.780 us; speedup vs baseline: 1.0665x; 1.0314x over previous
//
#include <hip/hip_runtime.h>

// toy_gnn scatter-add: out[dst[e], f] += w_mp * edge_weight[e] * x[src[e], f]
// N=100000, E=1600000, F=32, fp32.
//
// Round 9: occupancy + atomic-contention fixes.
//   R8 post-mortem: removing 38MB of record re-reads + one LDS pass moved
//   only -4.3us -> that work was L3-resident/overlapped, NOT critical path.
//   Revised theory: (a) bin_edges ran 512 thr x 256 blocks = 8 waves/CU (25%
//   occupancy) -- too few waves to hide scattered stores + LDS atomics;
//   (b) gcursor's 391 ints share 25 cachelines -> ~4K same-line global
//   atomics/line arriving in a synchronized burst (serializes at L2 bank);
//   (c) sort_gather's 16-wave blocks may exceed 64 VGPR -> 1 block/CU (50%).
//   Changes: bin_edges -> 1024 threads (16 waves/CU, run density unchanged
//   at 16 recs = 128B, avoiding the R5 fine-run regression); gcursor padded
//   to one counter per 128B line; sort_gather __launch_bounds__(1024, 8)
//   (VGPR cap 64 -> 2 blocks/CU; hand-counted hot-loop live set ~50).
//   Kept: R4 coarse layout, register accumulation (R5), no LDS fp32 atomics
//   (R6), single-pass record read + 256-counter LDS sort (R8).

constexpr int N_NODES = 100000;
constexpr int N_EDGES = 1600000;
constexpr int F_DIM   = 32;

// ---- binning (coarse) ----
constexpr int NPB_C = 256;                           // nodes per coarse bucket
constexpr int NB_C  = (N_NODES + NPB_C - 1) / NPB_C; // 391
constexpr int CAP_C = 4608;                          // mean 4096 + 8 sigma(64)

constexpr int CUR_STRIDE = 32;                       // ints; 128B per cursor line

constexpr int BIN_THREADS = 1024;                    // 16 waves/CU (was 8)
constexpr int BIN_BLOCKS  = 256;                     // one per CU
constexpr int BIN_CHUNK   = N_EDGES / BIN_BLOCKS;    // 6250 (exact)
constexpr int BIN_EPT     = (BIN_CHUNK + BIN_THREADS - 1) / BIN_THREADS;  // 7

// ---- fused sort+gather ----
constexpr int AGG_THREADS = 1024;                    // 16 waves
constexpr int GRPT = (CAP_C + AGG_THREADS - 1) / AGG_THREADS;  // 5

// ---------------- workspace layout (bytes) ----------------
constexpr size_t WS_CURSOR  = 0;                     // NB_C padded cursors
constexpr size_t WS_RECORDS = 64 * 1024;             // NB_C*CAP_C uint2
constexpr size_t WS_NEEDED  = WS_RECORDS + (size_t)NB_C * CAP_C * 8;  // ~14.5 MB

__global__ __launch_bounds__(BIN_THREADS) void bin_edges(
    const int* __restrict__ src, const int* __restrict__ dst,
    const float* __restrict__ ew, const float* __restrict__ w_mp,
    int* __restrict__ gcursor, uint2* __restrict__ records)
{
    __shared__ int lhist[NB_C];
    __shared__ int lbase[NB_C];
    if (threadIdx.x < NB_C) lhist[threadIdx.x] = 0;
    __syncthreads();

    const float w = w_mp[0];
    const int base_e = blockIdx.x * BIN_CHUNK;
    const int e_end  = min(base_e + BIN_CHUNK, N_EDGES);
    int   bkt[BIN_EPT];
    uint2 rec[BIN_EPT];

    #pragma unroll
    for (int i = 0; i < BIN_EPT; ++i) {
        int e = base_e + threadIdx.x + i * BIN_THREADS;
        bkt[i] = -1;
        if (e < e_end) {
            int d = dst[e];
            int b = d >> 8;                     // coarse bucket (256 nodes)
            bkt[i] = b;
            rec[i].x = __float_as_uint(w * ew[e]);
            rec[i].y = (unsigned)src[e] | ((unsigned)(d & 255) << 24);
            atomicAdd(&lhist[b], 1);
        }
    }
    __syncthreads();

    if (threadIdx.x < NB_C) {
        int c = lhist[threadIdx.x];
        // padded cursor: one counter per 128B cacheline -> no false sharing
        int base = c ? atomicAdd(&gcursor[threadIdx.x * CUR_STRIDE], c) : 0;
        lbase[threadIdx.x] = threadIdx.x * CAP_C + base;
        lhist[threadIdx.x] = 0;
    }
    __syncthreads();

    #pragma unroll
    for (int i = 0; i < BIN_EPT; ++i) {
        int b = bkt[i];
        if (b >= 0) {
            int pos = lbase[b] + atomicAdd(&lhist[b], 1);
            if (pos < (b + 1) * CAP_C)          // overflow guard (8-sigma margin)
                records[pos] = rec[i];
        }
    }
}

__global__ __launch_bounds__(AGG_THREADS, 8) void sort_gather(
    const int*   __restrict__ gcursor,
    const uint2* __restrict__ records,
    const float* __restrict__ x,
    float*       __restrict__ out)
{
    __shared__ uint2 sorted[CAP_C];      // 36.9 KB node-sorted records
    __shared__ int   hist[NPB_C];
    __shared__ int   offs[NPB_C + 1];
    __shared__ int   cursor[NPB_C];

    const int coarse = blockIdx.x;
    const int t      = threadIdx.x;

    if (t < NPB_C) hist[t] = 0;
    __syncthreads();

    // --- single global pass: records -> registers, histogram nodes ---
    const int rbase = coarse * CAP_C;
    const int cnt   = min(gcursor[coarse * CUR_STRIDE], CAP_C);

    uint2 rec[GRPT];
    #pragma unroll
    for (int i = 0; i < GRPT; ++i) {
        int j = t + i * AGG_THREADS;
        rec[i].y = 0xFFFFFFFFu;             // "empty" (src < 2^24 -> unambiguous)
        if (j < cnt) {
            rec[i] = records[rbase + j];
            atomicAdd(&hist[rec[i].y >> 24], 1);
        }
    }
    __syncthreads();

    // --- exclusive scan of 256 counters (wave 0, 4 per lane) ---
    if (t < 64) {
        const int b4 = t * 4;
        int h0 = hist[b4], h1 = hist[b4 + 1], h2 = hist[b4 + 2], h3 = hist[b4 + 3];
        int s   = h0 + h1 + h2 + h3;
        int inc = s;
        #pragma unroll
        for (int d = 1; d < 64; d <<= 1) {
            int o = __shfl_up(inc, d, 64);
            if (t >= d) inc += o;
        }
        int base = inc - s;                 // exclusive prefix of 4-groups
        offs[b4]     = base;
        offs[b4 + 1] = base + h0;
        offs[b4 + 2] = base + h0 + h1;
        offs[b4 + 3] = base + h0 + h1 + h2;
        cursor[b4]     = base;
        cursor[b4 + 1] = base + h0;
        cursor[b4 + 2] = base + h0 + h1;
        cursor[b4 + 3] = base + h0 + h1 + h2;
        if (t == 63) offs[NPB_C] = inc;
    }
    __syncthreads();

    // --- scatter registers -> sorted LDS (counting sort by node, 8 bits) ---
    #pragma unroll
    for (int i = 0; i < GRPT; ++i) {
        if (rec[i].y != 0xFFFFFFFFu) {
            int slot = atomicAdd(&cursor[rec[i].y >> 24], 1);
            sorted[slot] = rec[i];
        }
    }
    __syncthreads();

    // --- gather: 8 threads/node, register acc, 4-way unrolled x-loads ---
    const int qq = (t & 7) * 4;
    #pragma unroll
    for (int p = 0; p < 2; ++p) {
        const int node  = p * (AGG_THREADS / 8) + (t >> 3);
        const int gnode = coarse * NPB_C + node;
        if (gnode >= N_NODES) continue;

        int j  = offs[node];
        int je = offs[node + 1];
        float4 acc = make_float4(0.f, 0.f, 0.f, 0.f);

        for (; j + 4 <= je; j += 4) {
            uint2 r0 = sorted[j + 0];
            uint2 r1 = sorted[j + 1];
            uint2 r2 = sorted[j + 2];
            uint2 r3 = sorted[j + 3];
            const float4 v0 = *reinterpret_cast<const float4*>(
                x + (size_t)(r0.y & 0xFFFFFFu) * F_DIM + qq);
            const float4 v1 = *reinterpret_cast<const float4*>(
                x + (size_t)(r1.y & 0xFFFFFFu) * F_DIM + qq);
            const float4 v2 = *reinterpret_cast<const float4*>(
                x + (size_t)(r2.y & 0xFFFFFFu) * F_DIM + qq);
            const float4 v3 = *reinterpret_cast<const float4*>(
                x + (size_t)(r3.y & 0xFFFFFFu) * F_DIM + qq);
            float c0 = __uint_as_float(r0.x), c1 = __uint_as_float(r1.x);
            float c2 = __uint_as_float(r2.x), c3 = __uint_as_float(r3.x);
            acc.x += c0 * v0.x + c1 * v1.x + c2 * v2.x + c3 * v3.x;
            acc.y += c0 * v0.y + c1 * v1.y + c2 * v2.y + c3 * v3.y;
            acc.z += c0 * v0.z + c1 * v1.z + c2 * v2.z + c3 * v3.z;
            acc.w += c0 * v0.w + c1 * v1.w + c2 * v2.w + c3 * v3.w;
        }
        for (; j < je; ++j) {
            uint2 r = sorted[j];
            float c = __uint_as_float(r.x);
            const float4 v = *reinterpret_cast<const float4*>(
                x + (size_t)(r.y & 0xFFFFFFu) * F_DIM + qq);
            acc.x += c * v.x;
            acc.y += c * v.y;
            acc.z += c * v.z;
            acc.w += c * v.w;
        }
        *reinterpret_cast<float4*>(out + (size_t)gnode * F_DIM + qq) = acc;
    }
}

// ---------------- fallback (R0): plain atomic scatter ----------------
__global__ __launch_bounds__(256) void gnn_scatter_atomic(
    const float* __restrict__ x, const int* __restrict__ src,
    const int* __restrict__ dst, const float* __restrict__ ew,
    const float* __restrict__ w_mp, float* __restrict__ out)
{
    const float w = w_mp[0];
    int gid = blockIdx.x * blockDim.x + threadIdx.x;
    int e = gid >> 3;
    int qq = (gid & 7) * 4;
    if (e >= N_EDGES) return;
    int s = src[e];
    int d = dst[e];
    float c = w * ew[e];
    const float4 xv = *reinterpret_cast<const float4*>(x + (size_t)s * F_DIM + qq);
    float* op = out + (size_t)d * F_DIM + qq;
    atomicAdd(op + 0, c * xv.x);
    atomicAdd(op + 1, c * xv.y);
    atomicAdd(op + 2, c * xv.z);
    atomicAdd(op + 3, c * xv.w);
}

extern "C" void kernel_launch(void* const* d_in, const int* in_sizes, int n_in,
                              void* d_out, int out_size, void* d_ws, size_t ws_size,
                              hipStream_t stream) {
    const float* x    = (const float*)d_in[0];
    const int*   ei   = (const int*)d_in[1];   // [2, E]: src row, then dst row
    const float* ew   = (const float*)d_in[2];
    const float* w_mp = (const float*)d_in[3];
    float* out = (float*)d_out;

    const int* src = ei;
    const int* dst = ei + N_EDGES;

    if (ws_size < WS_NEEDED) {
        hipMemsetAsync(d_out, 0, (size_t)out_size * sizeof(float), stream);
        int total = N_EDGES * 8;
        gnn_scatter_atomic<<<(total + 255) / 256, 256, 0, stream>>>(
            x, src, dst, ew, w_mp, out);
        return;
    }

    char* ws = (char*)d_ws;
    int*   gcursor = (int*)(ws + WS_CURSOR);
    uint2* records = (uint2*)(ws + WS_RECORDS);

    hipMemsetAsync(gcursor, 0, NB_C * CUR_STRIDE * sizeof(int), stream);
    bin_edges<<<BIN_BLOCKS, BIN_THREADS, 0, stream>>>(src, dst, ew, w_mp,
                                                      gcursor, records);
    sort_gather<<<NB_C, AGG_THREADS, 0, stream>>>(gcursor, records, x, out);
    // sort_gather writes every out element -> no d_out memset needed
}